// Round 20
// baseline (804.743 us; speedup 1.0000x reference)
//
#include <hip/hip_runtime.h>
#include <hip/hip_bf16.h>

// QwenMoe: T=1024 H=2048 I=1408 E=60 SI=5632 topk=4, fp32 in/out.
// R20 = R19 (685us) + shared-gu M=256 per block (dual 128-row A-tiles per
// staged B step): shared-expert weight re-reads halve (8 -> 4 M-tiles,
// ~370 MB fabric saved). Routed gu path and all other kernels unchanged.

typedef float  f32x4  __attribute__((ext_vector_type(4)));
typedef short  bf16x8 __attribute__((ext_vector_type(8)));
typedef unsigned short u16;
typedef unsigned int   u32;

constexpr int TT = 1024, HD = 2048, ID = 1408, NE = 60, SID = 5632, KTOP = 4;
constexpr int NBR_GU = (ID / 128) * NE;                     // 660 routed gu blocks
constexpr int NBS_GU = (SID / 128) * (TT / 256);            // 176 shared gu blocks (M=256)
constexpr int NB_GU  = NBR_GU + NBS_GU;                     // 836
constexpr int NBS_DN = (HD / 128) * (TT / 128);             // 128 shared down blocks
constexpr int NB_DN  = NBS_DN + (HD / 128) * NE;            // +960 routed = 1088

#define GLDS(g, l) __builtin_amdgcn_global_load_lds( \
    (const __attribute__((address_space(1))) void*)(g), \
    (__attribute__((address_space(3))) void*)(l), 16, 0, 0)
#define GL4(dst, ptr) asm volatile("global_load_dwordx4 %0, %1, off" : "=&v"(dst) : "v"(ptr))
#define WAITVM(n) do { asm volatile("s_waitcnt vmcnt(" #n ")" ::: "memory"); \
                       __builtin_amdgcn_sched_barrier(0); } while (0)
#define BAR() do { asm volatile("" ::: "memory"); \
    __builtin_amdgcn_s_barrier(); \
    asm volatile("" ::: "memory"); } while (0)
#define LGKMBAR() do { asm volatile("s_waitcnt lgkmcnt(0)" ::: "memory"); \
    __builtin_amdgcn_s_barrier(); \
    asm volatile("" ::: "memory"); } while (0)

__device__ __forceinline__ u16 f2bf(float f) {
    union { float f; u32 u; } v; v.f = f;
    u32 r = v.u + 0x7FFFu + ((v.u >> 16) & 1u);   // RNE
    return (u16)(r >> 16);
}
__device__ __forceinline__ float bf2f(u16 b) {
    union { float f; u32 u; } v; v.u = ((u32)b) << 16; return v.f;
}
__device__ __forceinline__ u32 cvtpk(float a, float b) {
    u32 r; asm("v_cvt_pk_bf16_f32 %0, %1, %2" : "=v"(r) : "v"(a), "v"(b));
    return r;
}
__device__ __forceinline__ bf16x8 cvt8(f32x4 a, f32x4 b) {
    union { u32 u[4]; bf16x8 v; } rr;
    rr.u[0] = cvtpk(a[0], a[1]); rr.u[1] = cvtpk(a[2], a[3]);
    rr.u[2] = cvtpk(b[0], b[1]); rr.u[3] = cvtpk(b[2], b[3]);
    return rr.v;
}
// Bijective XCD swizzle (m204) over a HOMOGENEOUS block range only.
__device__ __forceinline__ int xcd_swz(int bid, int nwg) {
    int q = nwg >> 3, r = nwg & 7;
    int xcd = bid & 7, idx = bid >> 3;
    return (xcd < r ? xcd * (q + 1) : r * (q + 1) + (xcd - r) * q) + idx;
}

// merged count + prefix + scatter: single block, 1024 threads (= TT tokens).
__global__ __launch_bounds__(1024) void pscat_k(
    int* __restrict__ cntg, int* __restrict__ basea,
    const float* __restrict__ topk_p, const int* __restrict__ topk_i,
    int* __restrict__ slot_tok, float* __restrict__ slot_wt,
    int* __restrict__ slot_of)
{
    __shared__ int cnt_s[NE];
    __shared__ int base_s[NE];
    __shared__ int fill_s[NE];
    const int t = threadIdx.x;
    if (t < NE) { cnt_s[t] = 0; fill_s[t] = 0; }
    __syncthreads();
    int te[KTOP];
    #pragma unroll
    for (int k = 0; k < KTOP; k++) {
        te[k] = topk_i[t * KTOP + k];
        atomicAdd(&cnt_s[te[k]], 1);
    }
    __syncthreads();
    if (t == 0) {
        int s = 0;
        for (int j = 0; j < NE; j++) { base_s[j] = s; s += cnt_s[j]; }
    }
    __syncthreads();
    if (t < NE) { basea[t] = base_s[t]; cntg[t] = cnt_s[t]; }
    #pragma unroll
    for (int k = 0; k < KTOP; k++) {
        int e = te[k];
        int pos = atomicAdd(&fill_s[e], 1);
        int s = base_s[e] + pos;
        slot_tok[s] = t;
        slot_wt[s]  = topk_p[t * KTOP + k];
        slot_of[t * KTOP + k] = s;
    }
}

// gather: out[t][c] += sum_k bf16(dsl[slot_of[t][k]][c])
__global__ __launch_bounds__(256) void gather_k(
    const u16* __restrict__ dsl, const int* __restrict__ slot_of,
    float* __restrict__ out)
{
    const int t = blockIdx.x;
    const int c = threadIdx.x * 8;
    const int s0 = slot_of[t * 4 + 0], s1 = slot_of[t * 4 + 1];
    const int s2 = slot_of[t * 4 + 2], s3 = slot_of[t * 4 + 3];
    bf16x8 v0 = *(const bf16x8*)&dsl[(size_t)s0 * HD + c];
    bf16x8 v1 = *(const bf16x8*)&dsl[(size_t)s1 * HD + c];
    bf16x8 v2 = *(const bf16x8*)&dsl[(size_t)s2 * HD + c];
    bf16x8 v3 = *(const bf16x8*)&dsl[(size_t)s3 * HD + c];
    float* op = out + (size_t)t * HD + c;
    #pragma unroll
    for (int i = 0; i < 8; i++) {
        float s = bf2f((u16)v0[i]) + bf2f((u16)v1[i])
                + bf2f((u16)v2[i]) + bf2f((u16)v3[i]);
        op[i] += s;
    }
}

// ---------------- router: 4 tokens/block (one wave each) + fused x->bf16 ----
__global__ __launch_bounds__(256) void router_k(
    const float* __restrict__ x, const float* __restrict__ rw,
    const float* __restrict__ sgw,
    float* __restrict__ topk_p, int* __restrict__ topk_i,
    float* __restrict__ sgate, u16* __restrict__ xb)
{
    const int wv = threadIdx.x >> 6, l = threadIdx.x & 63;
    const int t = blockIdx.x * 4 + wv;
    const float4* xr = ((const float4*)(x + (size_t)t * HD)) + l * 8;
    float4 xa[8];
    #pragma unroll
    for (int i = 0; i < 8; i++) xa[i] = xr[i];

    {   // fused xcvt: lane l owns floats [l*32, l*32+32)
        u16* xo = xb + (size_t)t * HD + l * 32;
        #pragma unroll
        for (int i = 0; i < 4; i++) {
            uint4 o;
            o.x = cvtpk(xa[2*i].x, xa[2*i].y);
            o.y = cvtpk(xa[2*i].z, xa[2*i].w);
            o.z = cvtpk(xa[2*i+1].x, xa[2*i+1].y);
            o.w = cvtpk(xa[2*i+1].z, xa[2*i+1].w);
            *(uint4*)(xo + i * 8) = o;
        }
    }

    float le = 0.f;
    for (int e = 0; e < NE; e++) {
        const float4* wr = ((const float4*)(rw + (size_t)e * HD)) + l * 8;
        float a = 0.f;
        #pragma unroll
        for (int i = 0; i < 8; i++) {
            float4 wv_ = wr[i];
            a += xa[i].x * wv_.x + xa[i].y * wv_.y + xa[i].z * wv_.z + xa[i].w * wv_.w;
        }
        #pragma unroll
        for (int s = 32; s; s >>= 1) a += __shfl_xor(a, s);
        if (l == e) le = a;
    }
    {
        const float4* wr = ((const float4*)sgw) + l * 8;
        float a = 0.f;
        #pragma unroll
        for (int i = 0; i < 8; i++) {
            float4 wv_ = wr[i];
            a += xa[i].x * wv_.x + xa[i].y * wv_.y + xa[i].z * wv_.z + xa[i].w * wv_.w;
        }
        #pragma unroll
        for (int s = 32; s; s >>= 1) a += __shfl_xor(a, s);
        if (l == 0) sgate[t] = 1.f / (1.f + __expf(-a));
    }
    float mv = (l < NE) ? le : -3.4e38f;
    #pragma unroll
    for (int s = 32; s; s >>= 1) mv = fmaxf(mv, __shfl_xor(mv, s));
    float p = (l < NE) ? __expf(le - mv) : 0.f;
    float ss = p;
    #pragma unroll
    for (int s = 32; s; s >>= 1) ss += __shfl_xor(ss, s);
    p /= ss;
    float pv = (l < NE) ? p : -1.f;
    int   pi = l;
    float kp = 0.f; int ki = 0;
    for (int k = 0; k < KTOP; k++) {
        float bv = pv; int bi = pi;
        #pragma unroll
        for (int s = 32; s; s >>= 1) {
            float ov = __shfl_xor(bv, s); int oi = __shfl_xor(bi, s);
            if (ov > bv || (ov == bv && oi < bi)) { bv = ov; bi = oi; }
        }
        if (l == k) { kp = bv; ki = bi; }
        if (pi == bi) pv = -1.f;
    }
    if (l < KTOP) {
        topk_p[t * KTOP + l] = kp;
        topk_i[t * KTOP + l] = ki;
    }
}

// ======== fused GU: routed M=128 (R19 loop) | shared M=256 (dual A-tile).
// 128N tile, 512 thr, BK=32. A: GLDS bf16 4-buf depth-2. B: T14 reg->bf16.
__global__ __launch_bounds__(512) void gu_all(
    const u16* __restrict__ Xb,
    const float* __restrict__ w_gate, const float* __restrict__ w_up,
    const float* __restrict__ sw_g, const float* __restrict__ sw_u,
    u16* __restrict__ h, u16* __restrict__ hs,
    const int* __restrict__ slot_tok, const float* __restrict__ slot_wt,
    const int* __restrict__ cnt, const int* __restrict__ basea)
{
    __shared__ u16 Asl[4][256 * 32];    // 64 KB (routed uses first 128 rows)
    __shared__ u16 Bgsl[2][128 * 32];   // 16 KB
    __shared__ u16 Busl[2][128 * 32];   // 16 KB -> 96 KB total

    const int lidx = blockIdx.x;
    const int bid = (lidx < NBS_GU) ? (NBR_GU + lidx)
                                    : xcd_swz(lidx - NBS_GU, NBR_GU);
    const bool grouped = bid < NBR_GU;
    const int tid = threadIdx.x, w = tid >> 6, lane = tid & 63;
    const int lm = lane & 15, lk = lane >> 4;
    const int wm0 = (w >> 2) * 64, wn0 = (w & 3) * 32;

    int e = 0, my = 0, nb;
    const float *Wg, *Wu;
    if (grouped) {
        e = bid / 11; nb = bid % 11;
        Wg = w_gate + (size_t)e * ID * HD; Wu = w_up + (size_t)e * ID * HD;
    } else {
        int sid = bid - NBR_GU; my = sid / 44; nb = sid % 44;
        Wg = sw_g; Wu = sw_u;
    }

    const int ars = tid >> 2;
    const int aCh = (((tid & 3) ^ (ars & 3) ^ ((ars >> 2) & 3))) << 3;
    const int segA  = (w * 16) * 32;
    const int segA2 = (128 + w * 16) * 32;
    const int brt = tid >> 2, bkc = tid & 3;
    const float* pg = Wg + (size_t)(nb * 128 + brt) * HD + bkc * 8;
    const float* pu = Wu + (size_t)(nb * 128 + brt) * HD + bkc * 8;
    const int bWr = brt * 32 + ((bkc ^ ((brt >> 1) & 3)) << 3);

    int aOff[4], bOff[2];
    #pragma unroll
    for (int mf = 0; mf < 4; mf++) {
        int r = wm0 + mf * 16 + lm;
        aOff[mf] = r * 32 + ((lk ^ (r & 3) ^ ((r >> 2) & 3)) << 3);
    }
    #pragma unroll
    for (int nf = 0; nf < 2; nf++) {
        int rb = wn0 + nf * 16 + lm;
        bOff[nf] = rb * 32 + ((lk ^ ((rb >> 1) & 3)) << 3);
    }
    const int nk = HD >> 5;   // 64

    if (grouped) {
        const int mcnt  = cnt[e];
        const int mbase = basea[e];
        for (int mt = 0; mt * 128 < mcnt; ++mt) {
            const u16* aSrc;
            {
                int sl = mbase + mt * 128 + ars;
                int row = (mt * 128 + ars < mcnt) ? slot_tok[sl] : slot_tok[mbase];
                aSrc = Xb + (size_t)row * HD + aCh;
            }

            f32x4 accG[4][2], accU[4][2];
            #pragma unroll
            for (int mf = 0; mf < 4; mf++)
                #pragma unroll
                for (int nf = 0; nf < 2; nf++) {
                    accG[mf][nf] = f32x4{0.f, 0.f, 0.f, 0.f};
                    accU[mf][nf] = f32x4{0.f, 0.f, 0.f, 0.f};
                }

            f32x4 ga0, ga1, ua0, ua1;
            f32x4 gb0, gb1, ub0, ub1;

#define ISSUE(G0_, G1_, U0_, U1_, AB, KT) do {                                \
        GL4(G0_, pg + (KT)); GL4(G1_, pg + (KT) + 4);                         \
        GL4(U0_, pu + (KT)); GL4(U1_, pu + (KT) + 4);                         \
        GLDS(aSrc + (KT), &Asl[AB][segA]);                                    \
    } while (0)

#define WRITEB(G0_, G1_, U0_, U1_, BB) do {                                   \
        *(bf16x8*)&Bgsl[BB][bWr] = cvt8(G0_, G1_);                            \
        *(bf16x8*)&Busl[BB][bWr] = cvt8(U0_, U1_);                            \
    } while (0)

#define COMPSTEP(AB, BB) do {                                                 \
        bf16x8 af[4], bg[2], bu_[2];                                          \
        _Pragma("unroll")                                                     \
        for (int mf = 0; mf < 4; mf++) af[mf] = *(const bf16x8*)&Asl[AB][aOff[mf]]; \
        _Pragma("unroll")                                                     \
        for (int nf = 0; nf < 2; nf++) {                                      \
            bg[nf]  = *(const bf16x8*)&Bgsl[BB][bOff[nf]];                    \
            bu_[nf] = *(const bf16x8*)&Busl[BB][bOff[nf]];                    \
        }                                                                     \
        _Pragma("unroll")                                                     \
        for (int mf = 0; mf < 4; mf++)                                        \
            _Pragma("unroll")                                                 \
            for (int nf = 0; nf < 2; nf++) {                                  \
                accG[mf][nf] = __builtin_amdgcn_mfma_f32_16x16x32_bf16(af[mf], bg[nf],  accG[mf][nf], 0, 0, 0); \
                accU[mf][nf] = __builtin_amdgcn_mfma_f32_16x16x32_bf16(af[mf], bu_[nf], accU[mf][nf], 0, 0, 0); \
            }                                                                 \
    } while (0)

            ISSUE(ga0, ga1, ua0, ua1, 0, 0);
            ISSUE(gb0, gb1, ub0, ub1, 1, 32);
            WAITVM(5);
            WRITEB(ga0, ga1, ua0, ua1, 0);
            LGKMBAR();

            for (int t = 0; t < nk; t += 4) {
                if (t + 2 < nk) { ISSUE(ga0, ga1, ua0, ua1, 2, (t + 2) << 5); COMPSTEP(0, 0); WAITVM(5); }
                else            { COMPSTEP(0, 0); WAITVM(0); }
                if (t + 1 < nk) WRITEB(gb0, gb1, ub0, ub1, 1);
                LGKMBAR();
                if (t + 3 < nk) { ISSUE(gb0, gb1, ub0, ub1, 3, (t + 3) << 5); COMPSTEP(1, 1); WAITVM(5); }
                else            { COMPSTEP(1, 1); WAITVM(0); }
                if (t + 2 < nk) WRITEB(ga0, ga1, ua0, ua1, 0);
                LGKMBAR();
                if (t + 4 < nk) { ISSUE(ga0, ga1, ua0, ua1, 0, (t + 4) << 5); COMPSTEP(2, 0); WAITVM(5); }
                else            { COMPSTEP(2, 0); WAITVM(0); }
                if (t + 3 < nk) WRITEB(gb0, gb1, ub0, ub1, 1);
                LGKMBAR();
                if (t + 5 < nk) { ISSUE(gb0, gb1, ub0, ub1, 1, (t + 5) << 5); COMPSTEP(3, 1); WAITVM(5); }
                else            { COMPSTEP(3, 1); WAITVM(0); }
                if (t + 4 < nk) WRITEB(ga0, ga1, ua0, ua1, 0);
                LGKMBAR();
            }
#undef ISSUE
#undef WRITEB
#undef COMPSTEP

            #pragma unroll
            for (int mf = 0; mf < 4; mf++)
                #pragma unroll
                for (int j = 0; j < 4; j++) {
                    int m = wm0 + mf * 16 + lk * 4 + j;
                    if (mt * 128 + m < mcnt) {
                        size_t sl = (size_t)(mbase + mt * 128 + m);
                        float wt = slot_wt[sl];
                        #pragma unroll
                        for (int nf = 0; nf < 2; nf++) {
                            int col = nb * 128 + wn0 + nf * 16 + lm;
                            float g = accG[mf][nf][j], u = accU[mf][nf][j];
                            float hv = g / (1.f + __expf(-g)) * u * wt;
                            h[sl * (size_t)ID + col] = f2bf(hv);
                        }
                    }
                }
        }
    } else {
        // -------- shared expert: M=256 per block (two 128-row A-tiles) -----
        const u16* aSrc1 = Xb + (size_t)(my * 256 + ars) * HD + aCh;
        const u16* aSrc2 = aSrc1 + (size_t)128 * HD;

        f32x4 acG[4][2], acU[4][2];     // tile 1
        f32x4 acG2[4][2], acU2[4][2];   // tile 2
        #pragma unroll
        for (int mf = 0; mf < 4; mf++)
            #pragma unroll
            for (int nf = 0; nf < 2; nf++) {
                acG[mf][nf]  = f32x4{0.f, 0.f, 0.f, 0.f};
                acU[mf][nf]  = f32x4{0.f, 0.f, 0.f, 0.f};
                acG2[mf][nf] = f32x4{0.f, 0.f, 0.f, 0.f};
                acU2[mf][nf] = f32x4{0.f, 0.f, 0.f, 0.f};
            }

        f32x4 ga0, ga1, ua0, ua1;
        f32x4 gb0, gb1, ub0, ub1;

#define ISSUE2(G0_, G1_, U0_, U1_, AB, KT) do {                               \
        GL4(G0_, pg + (KT)); GL4(G1_, pg + (KT) + 4);                         \
        GL4(U0_, pu + (KT)); GL4(U1_, pu + (KT) + 4);                         \
        GLDS(aSrc1 + (KT), &Asl[AB][segA]);                                   \
        GLDS(aSrc2 + (KT), &Asl[AB][segA2]);                                  \
    } while (0)

#define WRITEB2(G0_, G1_, U0_, U1_, BB) do {                                  \
        *(bf16x8*)&Bgsl[BB][bWr] = cvt8(G0_, G1_);                            \
        *(bf16x8*)&Busl[BB][bWr] = cvt8(U0_, U1_);                            \
    } while (0)

#define COMPSTEP2(AB, BB) do {                                                \
        bf16x8 bg[2], bu_[2];                                                 \
        _Pragma("unroll")                                                     \
        for (int nf = 0; nf < 2; nf++) {                                      \
            bg[nf]  = *(const bf16x8*)&Bgsl[BB][bOff[nf]];                    \
            bu_[nf] = *(const bf16x8*)&Busl[BB][bOff[nf]];                    \
        }                                                                     \
        _Pragma("unroll")                                                     \
        for (int mf = 0; mf < 4; mf++) {                                      \
            bf16x8 af = *(const bf16x8*)&Asl[AB][aOff[mf]];                   \
            _Pragma("unroll")                                                 \
            for (int nf = 0; nf < 2; nf++) {                                  \
                acG[mf][nf] = __builtin_amdgcn_mfma_f32_16x16x32_bf16(af, bg[nf],  acG[mf][nf], 0, 0, 0); \
                acU[mf][nf] = __builtin_amdgcn_mfma_f32_16x16x32_bf16(af, bu_[nf], acU[mf][nf], 0, 0, 0); \
            }                                                                 \
        }                                                                     \
        _Pragma("unroll")                                                     \
        for (int mf = 0; mf < 4; mf++) {                                      \
            bf16x8 af = *(const bf16x8*)&Asl[AB][aOff[mf] + 128 * 32];        \
            _Pragma("unroll")                                                 \
            for (int nf = 0; nf < 2; nf++) {                                  \
                acG2[mf][nf] = __builtin_amdgcn_mfma_f32_16x16x32_bf16(af, bg[nf],  acG2[mf][nf], 0, 0, 0); \
                acU2[mf][nf] = __builtin_amdgcn_mfma_f32_16x16x32_bf16(af, bu_[nf], acU2[mf][nf], 0, 0, 0); \
            }                                                                 \
        }                                                                     \
    } while (0)

        ISSUE2(ga0, ga1, ua0, ua1, 0, 0);
        ISSUE2(gb0, gb1, ub0, ub1, 1, 32);
        WAITVM(6);
        WRITEB2(ga0, ga1, ua0, ua1, 0);
        LGKMBAR();

        for (int t = 0; t < nk; t += 4) {
            if (t + 2 < nk) { ISSUE2(ga0, ga1, ua0, ua1, 2, (t + 2) << 5); COMPSTEP2(0, 0); WAITVM(6); }
            else            { COMPSTEP2(0, 0); WAITVM(0); }
            if (t + 1 < nk) WRITEB2(gb0, gb1, ub0, ub1, 1);
            LGKMBAR();
            if (t + 3 < nk) { ISSUE2(gb0, gb1, ub0, ub1, 3, (t + 3) << 5); COMPSTEP2(1, 1); WAITVM(6); }
            else            { COMPSTEP2(1, 1); WAITVM(0); }
            if (t + 2 < nk) WRITEB2(ga0, ga1, ua0, ua1, 0);
            LGKMBAR();
            if (t + 4 < nk) { ISSUE2(ga0, ga1, ua0, ua1, 0, (t + 4) << 5); COMPSTEP2(2, 0); WAITVM(6); }
            else            { COMPSTEP2(2, 0); WAITVM(0); }
            if (t + 3 < nk) WRITEB2(gb0, gb1, ub0, ub1, 1);
            LGKMBAR();
            if (t + 5 < nk) { ISSUE2(gb0, gb1, ub0, ub1, 1, (t + 5) << 5); COMPSTEP2(3, 1); WAITVM(6); }
            else            { COMPSTEP2(3, 1); WAITVM(0); }
            if (t + 4 < nk) WRITEB2(ga0, ga1, ua0, ua1, 0);
            LGKMBAR();
        }
#undef ISSUE2
#undef WRITEB2
#undef COMPSTEP2

        #pragma unroll
        for (int mf = 0; mf < 4; mf++)
            #pragma unroll
            for (int j = 0; j < 4; j++) {
                int m = wm0 + mf * 16 + lk * 4 + j;
                size_t row1 = (size_t)(my * 256 + m);
                size_t row2 = row1 + 128;
                #pragma unroll
                for (int nf = 0; nf < 2; nf++) {
                    int col = nb * 128 + wn0 + nf * 16 + lm;
                    float g1 = acG[mf][nf][j], u1 = acU[mf][nf][j];
                    hs[row1 * (size_t)SID + col] = f2bf(g1 / (1.f + __expf(-g1)) * u1);
                    float g2 = acG2[mf][nf][j], u2 = acU2[mf][nf][j];
                    hs[row2 * (size_t)SID + col] = f2bf(g2 / (1.f + __expf(-g2)) * u2);
                }
            }
    }
}

// ======== fused DOWN (R19 verbatim): N-tile 128. shared (bid<128) + routed.
__global__ __launch_bounds__(256, 2) void down_all(
    const u16* __restrict__ h, const u16* __restrict__ hs,
    const float* __restrict__ w_down, const float* __restrict__ sw_d,
    float* __restrict__ outF, u16* __restrict__ dsl,
    const float* __restrict__ sgate,
    const int* __restrict__ cnt, const int* __restrict__ basea)
{
    __shared__ u16   Asl[3][128 * 32];   // 24 KB
    __shared__ float Bsl[3][128 * 32];   // 48 KB -> 72 KB total

    const int lidx = blockIdx.x;
    const int bid = (lidx < NBS_DN) ? lidx
                                    : (NBS_DN + xcd_swz(lidx - NBS_DN, NB_DN - NBS_DN));
    const bool shared_m = bid < NBS_DN;
    const int tid = threadIdx.x, w = tid >> 6, lane = tid & 63;
    const int lm = lane & 15, lk = lane >> 4;
    const int wm0 = (w >> 1) * 64, wn0 = (w & 1) * 64;

    int e = 0, my = 0, nb, K;
    const u16* Ap; const float* Wp;
    if (shared_m) {
        my = bid / 16; nb = bid % 16; K = SID; Ap = hs; Wp = sw_d;
    } else {
        int rid = bid - NBS_DN; e = rid / 16; nb = rid % 16; K = ID;
        Ap = h; Wp = w_down + (size_t)e * HD * ID;
    }
    const int mcnt  = shared_m ? 128 : cnt[e];
    const int mbase = shared_m ? 0 : basea[e];

    const int aCh = (((lane & 3) ^ ((lane >> 2) & 3) ^ ((lane >> 4) & 3))) << 3;
    const int bCh = ((lane & 7) ^ ((lane >> 3) & 7)) << 2;

    const float* bSrc[4];
    #pragma unroll
    for (int j = 0; j < 4; j++) {
        size_t rB = (size_t)(nb * 128 + w * 32 + j * 8 + (lane >> 3));
        bSrc[j] = Wp + rB * K + bCh;
    }

    int aOff[4], bOff[4][2];
    #pragma unroll
    for (int mf = 0; mf < 4; mf++) {
        int r = wm0 + mf * 16 + lm;
        aOff[mf] = r * 32 + ((lk ^ (r & 3) ^ ((r >> 2) & 3)) << 3);
    }
    #pragma unroll
    for (int nf = 0; nf < 4; nf++) {
        int rb = wn0 + nf * 16 + lm;
        bOff[nf][0] = rb * 32 + ((((lk << 1)    ) ^ (rb & 7)) << 2);
        bOff[nf][1] = rb * 32 + ((((lk << 1) | 1) ^ (rb & 7)) << 2);
    }

    const int nk = K >> 5;   // 176 shared, 44 routed

    for (int mt = 0; shared_m ? (mt == 0) : (mt * 128 < mcnt); ++mt) {
        const u16* aSrc[2];
        #pragma unroll
        for (int j = 0; j < 2; j++) {
            int mrow = w * 32 + j * 16 + (lane >> 2);
            size_t row = shared_m ? (size_t)(my * 128 + mrow)
                                  : (size_t)(mbase + mt * 128 + mrow);  // h padded
            aSrc[j] = Ap + row * K + aCh;
        }

        f32x4 acc[4][4];
        #pragma unroll
        for (int mf = 0; mf < 4; mf++)
            #pragma unroll
            for (int nf = 0; nf < 4; nf++) acc[mf][nf] = f32x4{0.f, 0.f, 0.f, 0.f};

        auto stage = [&](int b, int kt) {
            #pragma unroll
            for (int j = 0; j < 2; j++)
                GLDS(aSrc[j] + kt, &Asl[b][(w * 32 + j * 16) * 32]);
            #pragma unroll
            for (int j = 0; j < 4; j++)
                GLDS(bSrc[j] + kt, &Bsl[b][(w * 32 + j * 8) * 32]);
        };
        auto comp = [&](int b) {
            const u16*   At = Asl[b];
            const float* Bt = Bsl[b];
            bf16x8 af[4];
            #pragma unroll
            for (int mf = 0; mf < 4; mf++) af[mf] = *(const bf16x8*)&At[aOff[mf]];
            #pragma unroll
            for (int nf = 0; nf < 4; nf++) {
                bf16x8 bf_ = cvt8(*(const f32x4*)&Bt[bOff[nf][0]],
                                  *(const f32x4*)&Bt[bOff[nf][1]]);
                #pragma unroll
                for (int mf = 0; mf < 4; mf++)
                    acc[mf][nf] = __builtin_amdgcn_mfma_f32_16x16x32_bf16(af[mf], bf_, acc[mf][nf], 0, 0, 0);
            }
        };

        stage(0, 0); stage(1, 32);
        int t = 0, cb = 0;
        for (; t + 2 < nk; ++t) {
            int sbuf = cb - 1; if (sbuf < 0) sbuf += 3;    // (cb+2)%3
            stage(sbuf, (t + 2) << 5);
            WAITVM(12); BAR(); comp(cb); BAR();
            cb = (cb + 1 == 3) ? 0 : cb + 1;
        }
        WAITVM(6); BAR(); comp(cb); BAR();
        cb = (cb + 1 == 3) ? 0 : cb + 1;
        WAITVM(0); BAR(); comp(cb); BAR();

        #pragma unroll
        for (int mf = 0; mf < 4; mf++)
            #pragma unroll
            for (int j = 0; j < 4; j++) {
                int m = wm0 + mf * 16 + lk * 4 + j;
                if (mt * 128 + m < mcnt) {
                    if (shared_m) {
                        int tok = my * 128 + m;
                        float sc = sgate[tok];
                        #pragma unroll
                        for (int nf = 0; nf < 4; nf++) {
                            int col = nb * 128 + wn0 + nf * 16 + lm;
                            outF[(size_t)tok * HD + col] = sc * acc[mf][nf][j];
                        }
                    } else {
                        size_t srow = (size_t)(mbase + mt * 128 + m);
                        #pragma unroll
                        for (int nf = 0; nf < 4; nf++) {
                            int col = nb * 128 + wn0 + nf * 16 + lm;
                            dsl[srow * HD + col] = f2bf(acc[mf][nf][j]);
                        }
                    }
                }
            }
    }
}

extern "C" void kernel_launch(void* const* d_in, const int* in_sizes, int n_in,
                              void* d_out, int out_size, void* d_ws, size_t ws_size,
                              hipStream_t stream)
{
    const float* x      = (const float*)d_in[0];
    const float* rw     = (const float*)d_in[1];
    const float* w_gate = (const float*)d_in[2];
    const float* w_up   = (const float*)d_in[3];
    const float* w_down = (const float*)d_in[4];
    const float* sw_g   = (const float*)d_in[5];
    const float* sw_u   = (const float*)d_in[6];
    const float* sw_d   = (const float*)d_in[7];
    const float* sgw    = (const float*)d_in[8];
    float* out = (float*)d_out;

    char* ws = (char*)d_ws;
    int*   cnt      = (int*)(ws + 0);
    int*   basea    = (int*)(ws + 512);
    float* sgate    = (float*)(ws + 768);
    float* topk_p   = (float*)(ws + 5120);
    int*   topk_i   = (int*)(ws + 21504);
    int*   slot_tok = (int*)(ws + 37888);
    float* slot_wt  = (float*)(ws + 54272);
    u16*   xb = (u16*)(ws + 71680);              // [1024][2048] bf16
    u16*   h  = xb + (size_t)TT * HD;            // [4096+128][1408] bf16 (padded)
    u16*   hs = h + (size_t)(4096 + 128) * ID;   // [1024][5632] bf16
    u16*   dsl = hs + (size_t)TT * SID;          // [4224][2048] bf16
    int*   slot_of = (int*)(dsl + (size_t)(4096 + 128) * HD);  // [1024][4]

    router_k<<<TT / 4, 256, 0, stream>>>(x, rw, sgw, topk_p, topk_i, sgate, xb);
    pscat_k<<<1, 1024, 0, stream>>>(cnt, basea, topk_p, topk_i,
                                    slot_tok, slot_wt, slot_of);

    gu_all<<<NB_GU, 512, 0, stream>>>(
        xb, w_gate, w_up, sw_g, sw_u, h, hs,
        slot_tok, slot_wt, cnt, basea);

    down_all<<<NB_DN, 256, 0, stream>>>(
        h, hs, w_down, sw_d, out, dsl,
        sgate, cnt, basea);

    gather_k<<<TT, 256, 0, stream>>>(dsl, slot_of, out);
}

// Round 21
// 683.724 us; speedup vs baseline: 1.1770x; 1.1770x over previous
//
#include <hip/hip_runtime.h>
#include <hip/hip_bf16.h>

// QwenMoe: T=1024 H=2048 I=1408 E=60 SI=5632 topk=4, fp32 in/out.
// R21 = R19 verbatim (685us, session best). R20's M=256 shared-gu variant
// regressed to 805 (96KB LDS -> 1 blk/CU + reg-packed pipeline collapse);
// reverted per pre-committed decision rule.

typedef float  f32x4  __attribute__((ext_vector_type(4)));
typedef short  bf16x8 __attribute__((ext_vector_type(8)));
typedef unsigned short u16;
typedef unsigned int   u32;

constexpr int TT = 1024, HD = 2048, ID = 1408, NE = 60, SID = 5632, KTOP = 4;
constexpr int NBR_GU = (ID / 128) * NE;                     // 660 routed gu blocks
constexpr int NB_GU  = NBR_GU + (SID / 128) * (TT / 128);   // +352 shared = 1012
constexpr int NBS_DN = (HD / 128) * (TT / 128);             // 128 shared down blocks
constexpr int NB_DN  = NBS_DN + (HD / 128) * NE;            // +960 routed = 1088

#define GLDS(g, l) __builtin_amdgcn_global_load_lds( \
    (const __attribute__((address_space(1))) void*)(g), \
    (__attribute__((address_space(3))) void*)(l), 16, 0, 0)
#define GL4(dst, ptr) asm volatile("global_load_dwordx4 %0, %1, off" : "=&v"(dst) : "v"(ptr))
#define WAITVM(n) do { asm volatile("s_waitcnt vmcnt(" #n ")" ::: "memory"); \
                       __builtin_amdgcn_sched_barrier(0); } while (0)
#define BAR() do { asm volatile("" ::: "memory"); \
    __builtin_amdgcn_s_barrier(); \
    asm volatile("" ::: "memory"); } while (0)
#define LGKMBAR() do { asm volatile("s_waitcnt lgkmcnt(0)" ::: "memory"); \
    __builtin_amdgcn_s_barrier(); \
    asm volatile("" ::: "memory"); } while (0)

__device__ __forceinline__ u16 f2bf(float f) {
    union { float f; u32 u; } v; v.f = f;
    u32 r = v.u + 0x7FFFu + ((v.u >> 16) & 1u);   // RNE
    return (u16)(r >> 16);
}
__device__ __forceinline__ float bf2f(u16 b) {
    union { float f; u32 u; } v; v.u = ((u32)b) << 16; return v.f;
}
__device__ __forceinline__ u32 cvtpk(float a, float b) {
    u32 r; asm("v_cvt_pk_bf16_f32 %0, %1, %2" : "=v"(r) : "v"(a), "v"(b));
    return r;
}
__device__ __forceinline__ bf16x8 cvt8(f32x4 a, f32x4 b) {
    union { u32 u[4]; bf16x8 v; } rr;
    rr.u[0] = cvtpk(a[0], a[1]); rr.u[1] = cvtpk(a[2], a[3]);
    rr.u[2] = cvtpk(b[0], b[1]); rr.u[3] = cvtpk(b[2], b[3]);
    return rr.v;
}
// Bijective XCD swizzle (m204) over a HOMOGENEOUS block range only.
__device__ __forceinline__ int xcd_swz(int bid, int nwg) {
    int q = nwg >> 3, r = nwg & 7;
    int xcd = bid & 7, idx = bid >> 3;
    return (xcd < r ? xcd * (q + 1) : r * (q + 1) + (xcd - r) * q) + idx;
}

// merged count + prefix + scatter: single block, 1024 threads (= TT tokens).
__global__ __launch_bounds__(1024) void pscat_k(
    int* __restrict__ cntg, int* __restrict__ basea,
    const float* __restrict__ topk_p, const int* __restrict__ topk_i,
    int* __restrict__ slot_tok, float* __restrict__ slot_wt,
    int* __restrict__ slot_of)
{
    __shared__ int cnt_s[NE];
    __shared__ int base_s[NE];
    __shared__ int fill_s[NE];
    const int t = threadIdx.x;
    if (t < NE) { cnt_s[t] = 0; fill_s[t] = 0; }
    __syncthreads();
    int te[KTOP];
    #pragma unroll
    for (int k = 0; k < KTOP; k++) {
        te[k] = topk_i[t * KTOP + k];
        atomicAdd(&cnt_s[te[k]], 1);
    }
    __syncthreads();
    if (t == 0) {
        int s = 0;
        for (int j = 0; j < NE; j++) { base_s[j] = s; s += cnt_s[j]; }
    }
    __syncthreads();
    if (t < NE) { basea[t] = base_s[t]; cntg[t] = cnt_s[t]; }
    #pragma unroll
    for (int k = 0; k < KTOP; k++) {
        int e = te[k];
        int pos = atomicAdd(&fill_s[e], 1);
        int s = base_s[e] + pos;
        slot_tok[s] = t;
        slot_wt[s]  = topk_p[t * KTOP + k];
        slot_of[t * KTOP + k] = s;
    }
}

// gather: out[t][c] += sum_k bf16(dsl[slot_of[t][k]][c])
__global__ __launch_bounds__(256) void gather_k(
    const u16* __restrict__ dsl, const int* __restrict__ slot_of,
    float* __restrict__ out)
{
    const int t = blockIdx.x;
    const int c = threadIdx.x * 8;
    const int s0 = slot_of[t * 4 + 0], s1 = slot_of[t * 4 + 1];
    const int s2 = slot_of[t * 4 + 2], s3 = slot_of[t * 4 + 3];
    bf16x8 v0 = *(const bf16x8*)&dsl[(size_t)s0 * HD + c];
    bf16x8 v1 = *(const bf16x8*)&dsl[(size_t)s1 * HD + c];
    bf16x8 v2 = *(const bf16x8*)&dsl[(size_t)s2 * HD + c];
    bf16x8 v3 = *(const bf16x8*)&dsl[(size_t)s3 * HD + c];
    float* op = out + (size_t)t * HD + c;
    #pragma unroll
    for (int i = 0; i < 8; i++) {
        float s = bf2f((u16)v0[i]) + bf2f((u16)v1[i])
                + bf2f((u16)v2[i]) + bf2f((u16)v3[i]);
        op[i] += s;
    }
}

// ---------------- router: 4 tokens/block (one wave each) + fused x->bf16 ----
__global__ __launch_bounds__(256) void router_k(
    const float* __restrict__ x, const float* __restrict__ rw,
    const float* __restrict__ sgw,
    float* __restrict__ topk_p, int* __restrict__ topk_i,
    float* __restrict__ sgate, u16* __restrict__ xb)
{
    const int wv = threadIdx.x >> 6, l = threadIdx.x & 63;
    const int t = blockIdx.x * 4 + wv;
    const float4* xr = ((const float4*)(x + (size_t)t * HD)) + l * 8;
    float4 xa[8];
    #pragma unroll
    for (int i = 0; i < 8; i++) xa[i] = xr[i];

    {   // fused xcvt: lane l owns floats [l*32, l*32+32)
        u16* xo = xb + (size_t)t * HD + l * 32;
        #pragma unroll
        for (int i = 0; i < 4; i++) {
            uint4 o;
            o.x = cvtpk(xa[2*i].x, xa[2*i].y);
            o.y = cvtpk(xa[2*i].z, xa[2*i].w);
            o.z = cvtpk(xa[2*i+1].x, xa[2*i+1].y);
            o.w = cvtpk(xa[2*i+1].z, xa[2*i+1].w);
            *(uint4*)(xo + i * 8) = o;
        }
    }

    float le = 0.f;
    for (int e = 0; e < NE; e++) {
        const float4* wr = ((const float4*)(rw + (size_t)e * HD)) + l * 8;
        float a = 0.f;
        #pragma unroll
        for (int i = 0; i < 8; i++) {
            float4 wv_ = wr[i];
            a += xa[i].x * wv_.x + xa[i].y * wv_.y + xa[i].z * wv_.z + xa[i].w * wv_.w;
        }
        #pragma unroll
        for (int s = 32; s; s >>= 1) a += __shfl_xor(a, s);
        if (l == e) le = a;
    }
    {
        const float4* wr = ((const float4*)sgw) + l * 8;
        float a = 0.f;
        #pragma unroll
        for (int i = 0; i < 8; i++) {
            float4 wv_ = wr[i];
            a += xa[i].x * wv_.x + xa[i].y * wv_.y + xa[i].z * wv_.z + xa[i].w * wv_.w;
        }
        #pragma unroll
        for (int s = 32; s; s >>= 1) a += __shfl_xor(a, s);
        if (l == 0) sgate[t] = 1.f / (1.f + __expf(-a));
    }
    float mv = (l < NE) ? le : -3.4e38f;
    #pragma unroll
    for (int s = 32; s; s >>= 1) mv = fmaxf(mv, __shfl_xor(mv, s));
    float p = (l < NE) ? __expf(le - mv) : 0.f;
    float ss = p;
    #pragma unroll
    for (int s = 32; s; s >>= 1) ss += __shfl_xor(ss, s);
    p /= ss;
    float pv = (l < NE) ? p : -1.f;
    int   pi = l;
    float kp = 0.f; int ki = 0;
    for (int k = 0; k < KTOP; k++) {
        float bv = pv; int bi = pi;
        #pragma unroll
        for (int s = 32; s; s >>= 1) {
            float ov = __shfl_xor(bv, s); int oi = __shfl_xor(bi, s);
            if (ov > bv || (ov == bv && oi < bi)) { bv = ov; bi = oi; }
        }
        if (l == k) { kp = bv; ki = bi; }
        if (pi == bi) pv = -1.f;
    }
    if (l < KTOP) {
        topk_p[t * KTOP + l] = kp;
        topk_i[t * KTOP + l] = ki;
    }
}

// ======== fused GU: 128M x 128N tile, 512 thr, BK=32.
// Launch order: [0,352) shared (round-robin XCD), [352,1012) routed (swizzled).
__global__ __launch_bounds__(512, 2) void gu_all(
    const u16* __restrict__ Xb,
    const float* __restrict__ w_gate, const float* __restrict__ w_up,
    const float* __restrict__ sw_g, const float* __restrict__ sw_u,
    u16* __restrict__ h, u16* __restrict__ hs,
    const int* __restrict__ slot_tok, const float* __restrict__ slot_wt,
    const int* __restrict__ cnt, const int* __restrict__ basea)
{
    __shared__ u16 Asl[4][128 * 32];    // 32 KB
    __shared__ u16 Bgsl[2][128 * 32];   // 16 KB
    __shared__ u16 Busl[2][128 * 32];   // 16 KB -> 64 KB total

    const int lidx = blockIdx.x;
    const int bid = (lidx < NB_GU - NBR_GU) ? (NBR_GU + lidx)
                                            : xcd_swz(lidx - (NB_GU - NBR_GU), NBR_GU);
    const bool grouped = bid < NBR_GU;
    const int tid = threadIdx.x, w = tid >> 6, lane = tid & 63;
    const int lm = lane & 15, lk = lane >> 4;
    const int wm0 = (w >> 2) * 64, wn0 = (w & 3) * 32;

    int e = 0, my = 0, nb;
    const float *Wg, *Wu; u16* Hout; int Nout;
    if (grouped) {
        e = bid / 11; nb = bid % 11;
        Wg = w_gate + (size_t)e * ID * HD; Wu = w_up + (size_t)e * ID * HD;
        Hout = h; Nout = ID;
    } else {
        int sid = bid - NBR_GU; my = sid / 44; nb = sid % 44;
        Wg = sw_g; Wu = sw_u; Hout = hs; Nout = SID;
    }
    const int mcnt  = grouped ? cnt[e] : 128;
    const int mbase = grouped ? basea[e] : 0;

    const int ars = tid >> 2;
    const int aCh = (((tid & 3) ^ (ars & 3) ^ ((ars >> 2) & 3))) << 3;
    const int segA = (w * 16) * 32;
    const int brt = tid >> 2, bkc = tid & 3;
    const float* pg = Wg + (size_t)(nb * 128 + brt) * HD + bkc * 8;
    const float* pu = Wu + (size_t)(nb * 128 + brt) * HD + bkc * 8;
    const int bWr = brt * 32 + ((bkc ^ ((brt >> 1) & 3)) << 3);

    int aOff[4], bOff[2];
    #pragma unroll
    for (int mf = 0; mf < 4; mf++) {
        int r = wm0 + mf * 16 + lm;
        aOff[mf] = r * 32 + ((lk ^ (r & 3) ^ ((r >> 2) & 3)) << 3);
    }
    #pragma unroll
    for (int nf = 0; nf < 2; nf++) {
        int rb = wn0 + nf * 16 + lm;
        bOff[nf] = rb * 32 + ((lk ^ ((rb >> 1) & 3)) << 3);
    }
    const int nk = HD >> 5;   // 64

    for (int mt = 0; grouped ? (mt * 128 < mcnt) : (mt == 0); ++mt) {
        const u16* aSrc;
        {
            int row;
            if (grouped) {
                int sl = mbase + mt * 128 + ars;
                row = (mt * 128 + ars < mcnt) ? slot_tok[sl] : slot_tok[mbase];
            } else row = my * 128 + ars;
            aSrc = Xb + (size_t)row * HD + aCh;
        }

        f32x4 accG[4][2], accU[4][2];
        #pragma unroll
        for (int mf = 0; mf < 4; mf++)
            #pragma unroll
            for (int nf = 0; nf < 2; nf++) {
                accG[mf][nf] = f32x4{0.f, 0.f, 0.f, 0.f};
                accU[mf][nf] = f32x4{0.f, 0.f, 0.f, 0.f};
            }

        f32x4 ga0, ga1, ua0, ua1;
        f32x4 gb0, gb1, ub0, ub1;

#define ISSUE(G0_, G1_, U0_, U1_, AB, KT) do {                                \
        GL4(G0_, pg + (KT)); GL4(G1_, pg + (KT) + 4);                         \
        GL4(U0_, pu + (KT)); GL4(U1_, pu + (KT) + 4);                         \
        GLDS(aSrc + (KT), &Asl[AB][segA]);                                    \
    } while (0)

#define WRITEB(G0_, G1_, U0_, U1_, BB) do {                                   \
        *(bf16x8*)&Bgsl[BB][bWr] = cvt8(G0_, G1_);                            \
        *(bf16x8*)&Busl[BB][bWr] = cvt8(U0_, U1_);                            \
    } while (0)

#define COMPSTEP(AB, BB) do {                                                 \
        bf16x8 af[4], bg[2], bu_[2];                                          \
        _Pragma("unroll")                                                     \
        for (int mf = 0; mf < 4; mf++) af[mf] = *(const bf16x8*)&Asl[AB][aOff[mf]]; \
        _Pragma("unroll")                                                     \
        for (int nf = 0; nf < 2; nf++) {                                      \
            bg[nf]  = *(const bf16x8*)&Bgsl[BB][bOff[nf]];                    \
            bu_[nf] = *(const bf16x8*)&Busl[BB][bOff[nf]];                    \
        }                                                                     \
        _Pragma("unroll")                                                     \
        for (int mf = 0; mf < 4; mf++)                                        \
            _Pragma("unroll")                                                 \
            for (int nf = 0; nf < 2; nf++) {                                  \
                accG[mf][nf] = __builtin_amdgcn_mfma_f32_16x16x32_bf16(af[mf], bg[nf],  accG[mf][nf], 0, 0, 0); \
                accU[mf][nf] = __builtin_amdgcn_mfma_f32_16x16x32_bf16(af[mf], bu_[nf], accU[mf][nf], 0, 0, 0); \
            }                                                                 \
    } while (0)

        ISSUE(ga0, ga1, ua0, ua1, 0, 0);
        ISSUE(gb0, gb1, ub0, ub1, 1, 32);
        WAITVM(5);
        WRITEB(ga0, ga1, ua0, ua1, 0);
        LGKMBAR();

        for (int t = 0; t < nk; t += 4) {
            if (t + 2 < nk) { ISSUE(ga0, ga1, ua0, ua1, 2, (t + 2) << 5); COMPSTEP(0, 0); WAITVM(5); }
            else            { COMPSTEP(0, 0); WAITVM(0); }
            if (t + 1 < nk) WRITEB(gb0, gb1, ub0, ub1, 1);
            LGKMBAR();
            if (t + 3 < nk) { ISSUE(gb0, gb1, ub0, ub1, 3, (t + 3) << 5); COMPSTEP(1, 1); WAITVM(5); }
            else            { COMPSTEP(1, 1); WAITVM(0); }
            if (t + 2 < nk) WRITEB(ga0, ga1, ua0, ua1, 0);
            LGKMBAR();
            if (t + 4 < nk) { ISSUE(ga0, ga1, ua0, ua1, 0, (t + 4) << 5); COMPSTEP(2, 0); WAITVM(5); }
            else            { COMPSTEP(2, 0); WAITVM(0); }
            if (t + 3 < nk) WRITEB(gb0, gb1, ub0, ub1, 1);
            LGKMBAR();
            if (t + 5 < nk) { ISSUE(gb0, gb1, ub0, ub1, 1, (t + 5) << 5); COMPSTEP(3, 1); WAITVM(5); }
            else            { COMPSTEP(3, 1); WAITVM(0); }
            if (t + 4 < nk) WRITEB(ga0, ga1, ua0, ua1, 0);
            LGKMBAR();
        }
#undef ISSUE
#undef WRITEB
#undef COMPSTEP

        #pragma unroll
        for (int mf = 0; mf < 4; mf++)
            #pragma unroll
            for (int j = 0; j < 4; j++) {
                int m = wm0 + mf * 16 + lk * 4 + j;
                bool valid = grouped ? (mt * 128 + m < mcnt) : true;
                if (valid) {
                    size_t row; float wt;
                    if (grouped) {
                        size_t sl = (size_t)(mbase + mt * 128 + m);
                        row = sl; wt = slot_wt[sl];
                    } else { row = (size_t)(my * 128 + m); wt = 1.f; }
                    #pragma unroll
                    for (int nf = 0; nf < 2; nf++) {
                        int col = nb * 128 + wn0 + nf * 16 + lm;
                        float g = accG[mf][nf][j], u = accU[mf][nf][j];
                        float hv = g / (1.f + __expf(-g)) * u * wt;
                        Hout[row * (size_t)Nout + col] = f2bf(hv);
                    }
                }
            }
    }
}

// ======== fused DOWN: N-tile 128. shared (bid<128, K=5632) + routed (K=1408).
// 3-buf depth-2 GLDS pipeline, 6 VMEM/stage -> WAITVM(12)/(6)/(0).
// Atomic-free: shared overwrites out; routed stores bf16 to dsl[slot].
__global__ __launch_bounds__(256, 2) void down_all(
    const u16* __restrict__ h, const u16* __restrict__ hs,
    const float* __restrict__ w_down, const float* __restrict__ sw_d,
    float* __restrict__ outF, u16* __restrict__ dsl,
    const float* __restrict__ sgate,
    const int* __restrict__ cnt, const int* __restrict__ basea)
{
    __shared__ u16   Asl[3][128 * 32];   // 24 KB
    __shared__ float Bsl[3][128 * 32];   // 48 KB -> 72 KB total

    const int lidx = blockIdx.x;
    const int bid = (lidx < NBS_DN) ? lidx
                                    : (NBS_DN + xcd_swz(lidx - NBS_DN, NB_DN - NBS_DN));
    const bool shared_m = bid < NBS_DN;
    const int tid = threadIdx.x, w = tid >> 6, lane = tid & 63;
    const int lm = lane & 15, lk = lane >> 4;
    const int wm0 = (w >> 1) * 64, wn0 = (w & 1) * 64;

    int e = 0, my = 0, nb, K;
    const u16* Ap; const float* Wp;
    if (shared_m) {
        my = bid / 16; nb = bid % 16; K = SID; Ap = hs; Wp = sw_d;
    } else {
        int rid = bid - NBS_DN; e = rid / 16; nb = rid % 16; K = ID;
        Ap = h; Wp = w_down + (size_t)e * HD * ID;
    }
    const int mcnt  = shared_m ? 128 : cnt[e];
    const int mbase = shared_m ? 0 : basea[e];

    const int aCh = (((lane & 3) ^ ((lane >> 2) & 3) ^ ((lane >> 4) & 3))) << 3;
    const int bCh = ((lane & 7) ^ ((lane >> 3) & 7)) << 2;

    const float* bSrc[4];
    #pragma unroll
    for (int j = 0; j < 4; j++) {
        size_t rB = (size_t)(nb * 128 + w * 32 + j * 8 + (lane >> 3));
        bSrc[j] = Wp + rB * K + bCh;
    }

    int aOff[4], bOff[4][2];
    #pragma unroll
    for (int mf = 0; mf < 4; mf++) {
        int r = wm0 + mf * 16 + lm;
        aOff[mf] = r * 32 + ((lk ^ (r & 3) ^ ((r >> 2) & 3)) << 3);
    }
    #pragma unroll
    for (int nf = 0; nf < 4; nf++) {
        int rb = wn0 + nf * 16 + lm;
        bOff[nf][0] = rb * 32 + ((((lk << 1)    ) ^ (rb & 7)) << 2);
        bOff[nf][1] = rb * 32 + ((((lk << 1) | 1) ^ (rb & 7)) << 2);
    }

    const int nk = K >> 5;   // 176 shared, 44 routed

    for (int mt = 0; shared_m ? (mt == 0) : (mt * 128 < mcnt); ++mt) {
        const u16* aSrc[2];
        #pragma unroll
        for (int j = 0; j < 2; j++) {
            int mrow = w * 32 + j * 16 + (lane >> 2);
            size_t row = shared_m ? (size_t)(my * 128 + mrow)
                                  : (size_t)(mbase + mt * 128 + mrow);  // h padded
            aSrc[j] = Ap + row * K + aCh;
        }

        f32x4 acc[4][4];
        #pragma unroll
        for (int mf = 0; mf < 4; mf++)
            #pragma unroll
            for (int nf = 0; nf < 4; nf++) acc[mf][nf] = f32x4{0.f, 0.f, 0.f, 0.f};

        auto stage = [&](int b, int kt) {
            #pragma unroll
            for (int j = 0; j < 2; j++)
                GLDS(aSrc[j] + kt, &Asl[b][(w * 32 + j * 16) * 32]);
            #pragma unroll
            for (int j = 0; j < 4; j++)
                GLDS(bSrc[j] + kt, &Bsl[b][(w * 32 + j * 8) * 32]);
        };
        auto comp = [&](int b) {
            const u16*   At = Asl[b];
            const float* Bt = Bsl[b];
            bf16x8 af[4];
            #pragma unroll
            for (int mf = 0; mf < 4; mf++) af[mf] = *(const bf16x8*)&At[aOff[mf]];
            #pragma unroll
            for (int nf = 0; nf < 4; nf++) {
                bf16x8 bf_ = cvt8(*(const f32x4*)&Bt[bOff[nf][0]],
                                  *(const f32x4*)&Bt[bOff[nf][1]]);
                #pragma unroll
                for (int mf = 0; mf < 4; mf++)
                    acc[mf][nf] = __builtin_amdgcn_mfma_f32_16x16x32_bf16(af[mf], bf_, acc[mf][nf], 0, 0, 0);
            }
        };

        stage(0, 0); stage(1, 32);
        int t = 0, cb = 0;
        for (; t + 2 < nk; ++t) {
            int sbuf = cb - 1; if (sbuf < 0) sbuf += 3;    // (cb+2)%3
            stage(sbuf, (t + 2) << 5);
            WAITVM(12); BAR(); comp(cb); BAR();
            cb = (cb + 1 == 3) ? 0 : cb + 1;
        }
        WAITVM(6); BAR(); comp(cb); BAR();
        cb = (cb + 1 == 3) ? 0 : cb + 1;
        WAITVM(0); BAR(); comp(cb); BAR();

        #pragma unroll
        for (int mf = 0; mf < 4; mf++)
            #pragma unroll
            for (int j = 0; j < 4; j++) {
                int m = wm0 + mf * 16 + lk * 4 + j;
                if (mt * 128 + m < mcnt) {
                    if (shared_m) {
                        int tok = my * 128 + m;
                        float sc = sgate[tok];
                        #pragma unroll
                        for (int nf = 0; nf < 4; nf++) {
                            int col = nb * 128 + wn0 + nf * 16 + lm;
                            outF[(size_t)tok * HD + col] = sc * acc[mf][nf][j];
                        }
                    } else {
                        size_t srow = (size_t)(mbase + mt * 128 + m);
                        #pragma unroll
                        for (int nf = 0; nf < 4; nf++) {
                            int col = nb * 128 + wn0 + nf * 16 + lm;
                            dsl[srow * HD + col] = f2bf(acc[mf][nf][j]);
                        }
                    }
                }
            }
    }
}

extern "C" void kernel_launch(void* const* d_in, const int* in_sizes, int n_in,
                              void* d_out, int out_size, void* d_ws, size_t ws_size,
                              hipStream_t stream)
{
    const float* x      = (const float*)d_in[0];
    const float* rw     = (const float*)d_in[1];
    const float* w_gate = (const float*)d_in[2];
    const float* w_up   = (const float*)d_in[3];
    const float* w_down = (const float*)d_in[4];
    const float* sw_g   = (const float*)d_in[5];
    const float* sw_u   = (const float*)d_in[6];
    const float* sw_d   = (const float*)d_in[7];
    const float* sgw    = (const float*)d_in[8];
    float* out = (float*)d_out;

    char* ws = (char*)d_ws;
    int*   cnt      = (int*)(ws + 0);
    int*   basea    = (int*)(ws + 512);
    float* sgate    = (float*)(ws + 768);
    float* topk_p   = (float*)(ws + 5120);
    int*   topk_i   = (int*)(ws + 21504);
    int*   slot_tok = (int*)(ws + 37888);
    float* slot_wt  = (float*)(ws + 54272);
    u16*   xb = (u16*)(ws + 71680);              // [1024][2048] bf16
    u16*   h  = xb + (size_t)TT * HD;            // [4096+128][1408] bf16 (padded)
    u16*   hs = h + (size_t)(4096 + 128) * ID;   // [1024][5632] bf16
    u16*   dsl = hs + (size_t)TT * SID;          // [4224][2048] bf16
    int*   slot_of = (int*)(dsl + (size_t)(4096 + 128) * HD);  // [1024][4]

    router_k<<<TT / 4, 256, 0, stream>>>(x, rw, sgw, topk_p, topk_i, sgate, xb);
    pscat_k<<<1, 1024, 0, stream>>>(cnt, basea, topk_p, topk_i,
                                    slot_tok, slot_wt, slot_of);

    gu_all<<<NB_GU, 512, 0, stream>>>(
        xb, w_gate, w_up, sw_g, sw_u, h, hs,
        slot_tok, slot_wt, cnt, basea);

    down_all<<<NB_DN, 256, 0, stream>>>(
        h, hs, w_down, sw_d, out, dsl,
        sgate, cnt, basea);

    gather_k<<<TT, 256, 0, stream>>>(dsl, slot_of, out);
}